// Round 1
// baseline (726.757 us; speedup 1.0000x reference)
//
#include <hip/hip_runtime.h>

#define NN 20000
#define EE 660000      // 640000 + 20000 self loops
#define GG 64
#define FIN 114
#define H1 3
#define F1 342         // H1*FIN
#define D2 128
#define NEG 0.2f

// ---- float <-> monotone unsigned encoding for atomicMax on floats ----
__device__ inline unsigned fenc(float f) {
    unsigned u = __float_as_uint(f);
    return (u & 0x80000000u) ? ~u : (u | 0x80000000u);
}
__device__ inline float fdec(unsigned u) {
    return (u & 0x80000000u) ? __uint_as_float(u & 0x7FFFFFFFu) : __uint_as_float(~u);
}
__device__ inline float lrelu(float x) { return x > 0.f ? x : NEG * x; }

// ================= GEMM1: h1 = x @ W1   [N,114]x[114,342] =================
__global__ __launch_bounds__(384) void k_gemm1(const float* __restrict__ x,
                                               const float* __restrict__ W1,
                                               float* __restrict__ h1) {
    int rb = blockIdx.x * 8;
    int t = threadIdx.x;
    __shared__ float xs[8][FIN];
    for (int i = t; i < 8 * FIN; i += 384) {
        int r = i / FIN, k = i % FIN;
        int row = rb + r;
        xs[r][k] = (row < NN) ? x[row * FIN + k] : 0.f;
    }
    __syncthreads();
    if (t < F1) {
        float acc[8] = {0.f, 0.f, 0.f, 0.f, 0.f, 0.f, 0.f, 0.f};
        for (int k = 0; k < FIN; k++) {
            float w = W1[k * F1 + t];
#pragma unroll
            for (int r = 0; r < 8; r++) acc[r] += xs[r][k] * w;
        }
        for (int r = 0; r < 8; r++) {
            int row = rb + r;
            if (row < NN) h1[row * F1 + t] = acc[r];
        }
    }
}

// ============ alpha1: per-node per-head dot(h1_row, a_src/a_dst) ============
__global__ __launch_bounds__(192) void k_alpha1(const float* __restrict__ h1,
                                                const float* __restrict__ aS,
                                                const float* __restrict__ aD,
                                                float* __restrict__ as1,
                                                float* __restrict__ ad1) {
    int n = blockIdx.x;
    int w = threadIdx.x >> 6;   // head = wave
    int l = threadIdx.x & 63;
    const float* hr = h1 + n * F1 + w * FIN;
    float h0 = hr[l];
    float h1v = (l < FIN - 64) ? hr[64 + l] : 0.f;
    float s0 = aS[w * FIN + l], d0 = aD[w * FIN + l];
    float s1 = (l < FIN - 64) ? aS[w * FIN + 64 + l] : 0.f;
    float d1 = (l < FIN - 64) ? aD[w * FIN + 64 + l] : 0.f;
    float ps = h0 * s0 + h1v * s1;
    float pd = h0 * d0 + h1v * d1;
    for (int o = 32; o > 0; o >>= 1) {
        ps += __shfl_down(ps, o);
        pd += __shfl_down(pd, o);
    }
    if (l == 0) {
        as1[n * H1 + w] = ps;
        ad1[n * H1 + w] = pd;
    }
}

// ===================== CSR build =====================
__global__ void k_count(const int* __restrict__ dst, int* __restrict__ cnt) {
    int e = blockIdx.x * 256 + threadIdx.x;
    if (e < EE) atomicAdd(&cnt[dst[e]], 1);
}

__global__ __launch_bounds__(1024) void k_scan(const int* __restrict__ cnt,
                                               int* __restrict__ off) {
    __shared__ int part[1024];
    int t = threadIdx.x;
    const int CH = 20;   // 1024*20 >= 20000
    int loc[CH];
    int s = 0;
    int base = t * CH;
    for (int i = 0; i < CH; i++) {
        int idx = base + i;
        int v = (idx < NN) ? cnt[idx] : 0;
        loc[i] = s;
        s += v;
    }
    part[t] = s;
    __syncthreads();
    for (int d = 1; d < 1024; d <<= 1) {
        int v = (t >= d) ? part[t - d] : 0;
        __syncthreads();
        part[t] += v;
        __syncthreads();
    }
    int pre = (t == 0) ? 0 : part[t - 1];
    for (int i = 0; i < CH; i++) {
        int idx = base + i;
        if (idx < NN) off[idx] = pre + loc[i];
    }
    if (t == 1023) off[NN] = part[1023];
}

__global__ void k_scatter(const int* __restrict__ src, const int* __restrict__ dst,
                          const int* __restrict__ off, int* __restrict__ cur,
                          int* __restrict__ csr_src) {
    int e = blockIdx.x * 256 + threadIdx.x;
    if (e < EE) {
        int d = dst[e];
        int pos = off[d] + atomicAdd(&cur[d], 1);
        csr_src[pos] = src[e];
    }
}

// ================= layer-1 edge max / sum =================
__global__ void k_max1(const int* __restrict__ src, const int* __restrict__ dst,
                       const float* __restrict__ as1, const float* __restrict__ ad1,
                       unsigned* __restrict__ m1) {
    int e = blockIdx.x * 256 + threadIdx.x;
    if (e >= EE) return;
    int s = src[e], d = dst[e];
#pragma unroll
    for (int h = 0; h < H1; h++) {
        float ev = lrelu(as1[s * H1 + h] + ad1[d * H1 + h]);
        atomicMax(&m1[d * H1 + h], fenc(ev));
    }
}

__global__ void k_sum1(const int* __restrict__ src, const int* __restrict__ dst,
                       const float* __restrict__ as1, const float* __restrict__ ad1,
                       const unsigned* __restrict__ m1, float* __restrict__ s1) {
    int e = blockIdx.x * 256 + threadIdx.x;
    if (e >= EE) return;
    int s = src[e], d = dst[e];
#pragma unroll
    for (int h = 0; h < H1; h++) {
        float ev = lrelu(as1[s * H1 + h] + ad1[d * H1 + h]);
        float ex = expf(ev - fdec(m1[d * H1 + h]));
        atomicAdd(&s1[d * H1 + h], ex);
    }
}

// ================= layer-1 aggregation (per dst node) =================
__global__ __launch_bounds__(128) void k_agg1(const float* __restrict__ h1,
                                              const float* __restrict__ as1,
                                              const float* __restrict__ ad1,
                                              const unsigned* __restrict__ m1,
                                              const float* __restrict__ s1,
                                              const int* __restrict__ off,
                                              const int* __restrict__ csr_src,
                                              const float* __restrict__ b1,
                                              float* __restrict__ h1a) {
    int n = blockIdx.x;
    int t = threadIdx.x;
    __shared__ int ssrc[64];
    __shared__ float salp[64][H1];
    float mdec[H1], sinv[H1], adv[H1];
#pragma unroll
    for (int h = 0; h < H1; h++) {
        mdec[h] = fdec(m1[n * H1 + h]);
        sinv[h] = 1.0f / s1[n * H1 + h];
        adv[h] = ad1[n * H1 + h];
    }
    int e0 = off[n], e1 = off[n + 1];
    float acc0 = 0.f, acc1 = 0.f, acc2 = 0.f;
    int f0 = t, f1v = t + 128, f2 = t + 256;
    int hh0 = f0 / FIN, hh1 = f1v / FIN;
    int hh2 = (f2 < F1) ? (f2 / FIN) : 0;
    for (int base = e0; base < e1; base += 64) {
        int c = min(64, e1 - base);
        if (t < c) {
            int s = csr_src[base + t];
            ssrc[t] = s;
#pragma unroll
            for (int h = 0; h < H1; h++) {
                float ev = lrelu(as1[s * H1 + h] + adv[h]);
                salp[t][h] = expf(ev - mdec[h]) * sinv[h];
            }
        }
        __syncthreads();
        for (int j = 0; j < c; j++) {
            int s = ssrc[j];
            const float* hr = h1 + s * F1;
            acc0 += hr[f0] * salp[j][hh0];
            acc1 += hr[f1v] * salp[j][hh1];
            if (f2 < F1) acc2 += hr[f2] * salp[j][hh2];
        }
        __syncthreads();
    }
    // epilogue: +b1, ELU
    float v0 = acc0 + b1[f0];
    float v1 = acc1 + b1[f1v];
    h1a[n * F1 + f0] = v0 > 0.f ? v0 : expm1f(v0);
    h1a[n * F1 + f1v] = v1 > 0.f ? v1 : expm1f(v1);
    if (f2 < F1) {
        float v2 = acc2 + b1[f2];
        h1a[n * F1 + f2] = v2 > 0.f ? v2 : expm1f(v2);
    }
}

// ================= GEMM2: h2 = h1a @ W2   [N,342]x[342,128] =================
__global__ __launch_bounds__(128) void k_gemm2(const float* __restrict__ h1a,
                                               const float* __restrict__ W2,
                                               float* __restrict__ h2) {
    int rb = blockIdx.x * 8;
    int t = threadIdx.x;
    __shared__ float xs[8][F1];
    for (int i = t; i < 8 * F1; i += 128) {
        int r = i / F1, k = i % F1;
        int row = rb + r;
        xs[r][k] = (row < NN) ? h1a[row * F1 + k] : 0.f;
    }
    __syncthreads();
    float acc[8] = {0.f, 0.f, 0.f, 0.f, 0.f, 0.f, 0.f, 0.f};
    for (int k = 0; k < F1; k++) {
        float w = W2[k * D2 + t];
#pragma unroll
        for (int r = 0; r < 8; r++) acc[r] += xs[r][k] * w;
    }
    for (int r = 0; r < 8; r++) {
        int row = rb + r;
        if (row < NN) h2[row * D2 + t] = acc[r];
    }
}

// ============ alpha2: per-node dot(h2_row, a_src2/a_dst2), 1 head ============
__global__ __launch_bounds__(256) void k_alpha2(const float* __restrict__ h2,
                                                const float* __restrict__ aS,
                                                const float* __restrict__ aD,
                                                float* __restrict__ as2,
                                                float* __restrict__ ad2) {
    int n = blockIdx.x * 4 + (threadIdx.x >> 6);
    int l = threadIdx.x & 63;
    if (n >= NN) return;
    float v0 = h2[n * D2 + l], v1 = h2[n * D2 + 64 + l];
    float ps = v0 * aS[l] + v1 * aS[64 + l];
    float pd = v0 * aD[l] + v1 * aD[64 + l];
    for (int o = 32; o > 0; o >>= 1) {
        ps += __shfl_down(ps, o);
        pd += __shfl_down(pd, o);
    }
    if (l == 0) {
        as2[n] = ps;
        ad2[n] = pd;
    }
}

// ================= layer-2 edge max / sum =================
__global__ void k_max2(const int* __restrict__ src, const int* __restrict__ dst,
                       const float* __restrict__ as2, const float* __restrict__ ad2,
                       unsigned* __restrict__ m2) {
    int e = blockIdx.x * 256 + threadIdx.x;
    if (e >= EE) return;
    float ev = lrelu(as2[src[e]] + ad2[dst[e]]);
    atomicMax(&m2[dst[e]], fenc(ev));
}

__global__ void k_sum2(const int* __restrict__ src, const int* __restrict__ dst,
                       const float* __restrict__ as2, const float* __restrict__ ad2,
                       const unsigned* __restrict__ m2, float* __restrict__ s2) {
    int e = blockIdx.x * 256 + threadIdx.x;
    if (e >= EE) return;
    int d = dst[e];
    float ev = lrelu(as2[src[e]] + ad2[d]);
    atomicAdd(&s2[d], expf(ev - fdec(m2[d])));
}

// ================= layer-2 aggregation =================
__global__ __launch_bounds__(128) void k_agg2(const float* __restrict__ h2,
                                              const float* __restrict__ as2,
                                              const float* __restrict__ ad2,
                                              const unsigned* __restrict__ m2,
                                              const float* __restrict__ s2,
                                              const int* __restrict__ off,
                                              const int* __restrict__ csr_src,
                                              const float* __restrict__ b2,
                                              float* __restrict__ h3) {
    int n = blockIdx.x;
    int t = threadIdx.x;
    __shared__ int ssrc[64];
    __shared__ float salp[64];
    float md = fdec(m2[n]);
    float si = 1.0f / s2[n];
    float adv = ad2[n];
    int e0 = off[n], e1 = off[n + 1];
    float acc = 0.f;
    for (int base = e0; base < e1; base += 64) {
        int c = min(64, e1 - base);
        if (t < c) {
            int s = csr_src[base + t];
            ssrc[t] = s;
            float ev = lrelu(as2[s] + adv);
            salp[t] = expf(ev - md) * si;
        }
        __syncthreads();
        for (int j = 0; j < c; j++) acc += h2[ssrc[j] * D2 + t] * salp[j];
        __syncthreads();
    }
    h3[n * D2 + t] = fmaxf(acc + b2[t], 0.f);
}

// ================= pool (segment max) + MLP head =================
__global__ __launch_bounds__(128) void k_pool_mlp(const float* __restrict__ h3,
                                                  const float* __restrict__ Wg,
                                                  const float* __restrict__ bg,
                                                  const float* __restrict__ Wf1,
                                                  const float* __restrict__ bf1,
                                                  const float* __restrict__ Wf2,
                                                  const float* __restrict__ bf2,
                                                  const float* __restrict__ Wo,
                                                  const float* __restrict__ bo,
                                                  float* __restrict__ out) {
    int g = blockIdx.x;
    int t = threadIdx.x;
    __shared__ float pool[D2];
    __shared__ float a1[64];
    __shared__ float a2[32];
    __shared__ float a3[16];
    int n0 = (g * NN + GG - 1) / GG;
    int n1 = ((g + 1) * NN + GG - 1) / GG;
    float mx = -1e30f;
    for (int n = n0; n < n1; n++) mx = fmaxf(mx, h3[n * D2 + t]);
    pool[t] = mx;
    __syncthreads();
    if (t < 64) {
        float acc = bg[t];
        for (int k = 0; k < D2; k++) acc += pool[k] * Wg[k * 64 + t];
        a1[t] = fmaxf(acc, 0.f);
    }
    __syncthreads();
    if (t < 32) {
        float acc = bf1[t];
        for (int k = 0; k < 64; k++) acc += a1[k] * Wf1[k * 32 + t];
        a2[t] = fmaxf(acc, 0.f);
    }
    __syncthreads();
    if (t < 16) {
        float acc = bf2[t];
        for (int k = 0; k < 32; k++) acc += a2[k] * Wf2[k * 16 + t];
        a3[t] = fmaxf(acc, 0.f);
    }
    __syncthreads();
    if (t == 0) {
        float acc = bo[0];
        for (int k = 0; k < 16; k++) acc += a3[k] * Wo[k];
        out[g] = acc;
    }
}

extern "C" void kernel_launch(void* const* d_in, const int* in_sizes, int n_in,
                              void* d_out, int out_size, void* d_ws, size_t ws_size,
                              hipStream_t stream) {
    const float* x = (const float*)d_in[0];
    const int* ei = (const int*)d_in[1];       // [2, EE] row-major
    // d_in[2] = batch (unused: batch = n*G//N, computed analytically)
    const float* W1 = (const float*)d_in[3];
    const float* aS1 = (const float*)d_in[4];
    const float* aD1 = (const float*)d_in[5];
    const float* b1 = (const float*)d_in[6];
    const float* W2 = (const float*)d_in[7];
    const float* aS2 = (const float*)d_in[8];
    const float* aD2 = (const float*)d_in[9];
    const float* b2 = (const float*)d_in[10];
    const float* Wg = (const float*)d_in[11];
    const float* bg = (const float*)d_in[12];
    const float* Wf1 = (const float*)d_in[13];
    const float* bf1 = (const float*)d_in[14];
    const float* Wf2 = (const float*)d_in[15];
    const float* bf2 = (const float*)d_in[16];
    const float* Wo = (const float*)d_in[17];
    const float* bo = (const float*)d_in[18];
    float* out = (float*)d_out;

    const int* src = ei;
    const int* dst = ei + EE;

    // ---- workspace layout ----
    char* ws = (char*)d_ws;
    size_t o = 0;
    auto alloc = [&](size_t bytes) -> char* {
        char* p = ws + o;
        o += (bytes + 255) & ~(size_t)255;
        return p;
    };
    float* h1 = (float*)alloc((size_t)NN * F1 * 4);
    float* as1 = (float*)alloc((size_t)NN * H1 * 4);
    float* ad1 = (float*)alloc((size_t)NN * H1 * 4);
    unsigned* m1 = (unsigned*)alloc((size_t)NN * H1 * 4);
    float* s1 = (float*)alloc((size_t)NN * H1 * 4);
    int* cnt = (int*)alloc((size_t)NN * 4);
    int* off = (int*)alloc((size_t)(NN + 1) * 4);
    int* cur = (int*)alloc((size_t)NN * 4);
    int* csr_src = (int*)alloc((size_t)EE * 4);
    float* h1a = (float*)alloc((size_t)NN * F1 * 4);
    float* h2 = (float*)alloc((size_t)NN * D2 * 4);
    float* as2 = (float*)alloc((size_t)NN * 4);
    float* ad2 = (float*)alloc((size_t)NN * 4);
    unsigned* m2 = (unsigned*)alloc((size_t)NN * 4);
    float* s2 = (float*)alloc((size_t)NN * 4);
    float* h3 = (float*)alloc((size_t)NN * D2 * 4);
    (void)ws_size;

    // ---- zero-init accumulators (every launch: harness doesn't re-poison) ----
    hipMemsetAsync(m1, 0, (size_t)NN * H1 * 4, stream);   // 0 == fenc(-inf)
    hipMemsetAsync(s1, 0, (size_t)NN * H1 * 4, stream);
    hipMemsetAsync(cnt, 0, (size_t)NN * 4, stream);
    hipMemsetAsync(cur, 0, (size_t)NN * 4, stream);
    hipMemsetAsync(m2, 0, (size_t)NN * 4, stream);
    hipMemsetAsync(s2, 0, (size_t)NN * 4, stream);

    const int EB = (EE + 255) / 256;

    // layer 1
    k_gemm1<<<(NN + 7) / 8, 384, 0, stream>>>(x, W1, h1);
    k_alpha1<<<NN, 192, 0, stream>>>(h1, aS1, aD1, as1, ad1);
    k_count<<<EB, 256, 0, stream>>>(dst, cnt);
    k_scan<<<1, 1024, 0, stream>>>(cnt, off);
    k_scatter<<<EB, 256, 0, stream>>>(src, dst, off, cur, csr_src);
    k_max1<<<EB, 256, 0, stream>>>(src, dst, as1, ad1, m1);
    k_sum1<<<EB, 256, 0, stream>>>(src, dst, as1, ad1, m1, s1);
    k_agg1<<<NN, 128, 0, stream>>>(h1, as1, ad1, m1, s1, off, csr_src, b1, h1a);

    // layer 2
    k_gemm2<<<(NN + 7) / 8, 128, 0, stream>>>(h1a, W2, h2);
    k_alpha2<<<(NN + 3) / 4, 256, 0, stream>>>(h2, aS2, aD2, as2, ad2);
    k_max2<<<EB, 256, 0, stream>>>(src, dst, as2, ad2, m2);
    k_sum2<<<EB, 256, 0, stream>>>(src, dst, as2, ad2, m2, s2);
    k_agg2<<<NN, 128, 0, stream>>>(h2, as2, ad2, m2, s2, off, csr_src, b2, h3);

    // pool + MLP head
    k_pool_mlp<<<GG, 128, 0, stream>>>(h3, Wg, bg, Wf1, bf1, Wf2, bf2, Wo, bo, out);
}

// Round 2
// 439.241 us; speedup vs baseline: 1.6546x; 1.6546x over previous
//
#include <hip/hip_runtime.h>

#define NN 20000
#define EE 660000      // 640000 + 20000 self loops
#define GG 64
#define FIN 114
#define H1 3
#define F1 342         // H1*FIN
#define D2 128
#define NEG 0.2f

__device__ inline unsigned fenc(float f) {
    unsigned u = __float_as_uint(f);
    return (u & 0x80000000u) ? ~u : (u | 0x80000000u);
}
__device__ inline float fdec(unsigned u) {
    return (u & 0x80000000u) ? __uint_as_float(u & 0x7FFFFFFFu) : __uint_as_float(~u);
}
__device__ inline float lrelu(float x) { return x > 0.f ? x : NEG * x; }

// ===== fold a_src/a_dst through W1: was[k*3+h] = sum_d W1[k, h*114+d] * aS[h,d] =====
__global__ void k_wa(const float* __restrict__ W1, const float* __restrict__ aS,
                     const float* __restrict__ aD, float* __restrict__ was,
                     float* __restrict__ wad) {
    int tid = blockIdx.x * 256 + threadIdx.x;
    if (tid >= 2 * FIN * H1) return;
    int which = tid >= FIN * H1;
    int i = which ? tid - FIN * H1 : tid;
    int k = i / H1, h = i % H1;
    const float* a = which ? aD : aS;
    float s = 0.f;
    for (int d = 0; d < FIN; d++) s += W1[k * F1 + h * FIN + d] * a[h * FIN + d];
    (which ? wad : was)[i] = s;
}

// ===== as1/ad1 = x @ was/wad  (per node, 6 dots of length 114) =====
__global__ __launch_bounds__(256) void k_alpha1x(const float* __restrict__ x,
                                                 const float* __restrict__ was,
                                                 const float* __restrict__ wad,
                                                 float* __restrict__ as1,
                                                 float* __restrict__ ad1) {
    int n = blockIdx.x * 4 + (threadIdx.x >> 6);
    int l = threadIdx.x & 63;
    if (n >= NN) return;
    float x0 = x[n * FIN + l];
    float x1 = (l < FIN - 64) ? x[n * FIN + 64 + l] : 0.f;
    float s[H1], d[H1];
#pragma unroll
    for (int h = 0; h < H1; h++) {
        float w0s = was[l * H1 + h], w0d = wad[l * H1 + h];
        float w1s = (l < FIN - 64) ? was[(64 + l) * H1 + h] : 0.f;
        float w1d = (l < FIN - 64) ? wad[(64 + l) * H1 + h] : 0.f;
        s[h] = x0 * w0s + x1 * w1s;
        d[h] = x0 * w0d + x1 * w1d;
    }
#pragma unroll
    for (int o = 32; o > 0; o >>= 1) {
#pragma unroll
        for (int h = 0; h < H1; h++) {
            s[h] += __shfl_down(s[h], o);
            d[h] += __shfl_down(d[h], o);
        }
    }
    if (l == 0) {
#pragma unroll
        for (int h = 0; h < H1; h++) {
            as1[n * H1 + h] = s[h];
            ad1[n * H1 + h] = d[h];
        }
    }
}

// ===================== CSR build =====================
__global__ void k_count(const int* __restrict__ dst, int* __restrict__ cnt) {
    int e = blockIdx.x * 256 + threadIdx.x;
    if (e < EE) atomicAdd(&cnt[dst[e]], 1);
}

__global__ __launch_bounds__(1024) void k_scan(const int* __restrict__ cnt,
                                               int* __restrict__ off) {
    __shared__ int part[1024];
    int t = threadIdx.x;
    const int CH = 20;
    int loc[CH];
    int s = 0;
    int base = t * CH;
    for (int i = 0; i < CH; i++) {
        int idx = base + i;
        int v = (idx < NN) ? cnt[idx] : 0;
        loc[i] = s;
        s += v;
    }
    part[t] = s;
    __syncthreads();
    for (int d = 1; d < 1024; d <<= 1) {
        int v = (t >= d) ? part[t - d] : 0;
        __syncthreads();
        part[t] += v;
        __syncthreads();
    }
    int pre = (t == 0) ? 0 : part[t - 1];
    for (int i = 0; i < CH; i++) {
        int idx = base + i;
        if (idx < NN) off[idx] = pre + loc[i];
    }
    if (t == 1023) off[NN] = part[1023];
}

__global__ void k_scatter(const int* __restrict__ src, const int* __restrict__ dst,
                          const int* __restrict__ off, int* __restrict__ cur,
                          int* __restrict__ csr_src) {
    int e = blockIdx.x * 256 + threadIdx.x;
    if (e < EE) {
        int d = dst[e];
        int pos = off[d] + atomicAdd(&cur[d], 1);
        csr_src[pos] = src[e];
    }
}

// ===== layer-1: fused max/softmax-sum/aggregate of x into xagg [N,3,114] =====
__global__ __launch_bounds__(128) void k_aggx(const float* __restrict__ x,
                                              const float* __restrict__ as1,
                                              const float* __restrict__ ad1,
                                              const int* __restrict__ off,
                                              const int* __restrict__ csr_src,
                                              float* __restrict__ xagg) {
    int n = blockIdx.x, t = threadIdx.x;
    int e0 = off[n], e1 = off[n + 1];
    float adv0 = ad1[n * H1 + 0], adv1 = ad1[n * H1 + 1], adv2 = ad1[n * H1 + 2];
    // phase 1: per-head max over incoming edges
    float m0 = -1e30f, m1 = -1e30f, m2 = -1e30f;
    for (int e = e0 + t; e < e1; e += 128) {
        int s = csr_src[e];
        m0 = fmaxf(m0, lrelu(as1[s * H1 + 0] + adv0));
        m1 = fmaxf(m1, lrelu(as1[s * H1 + 1] + adv1));
        m2 = fmaxf(m2, lrelu(as1[s * H1 + 2] + adv2));
    }
    __shared__ float red[128][H1];
    red[t][0] = m0; red[t][1] = m1; red[t][2] = m2;
    __syncthreads();
    for (int sr = 64; sr > 0; sr >>= 1) {
        if (t < sr) {
            red[t][0] = fmaxf(red[t][0], red[t + sr][0]);
            red[t][1] = fmaxf(red[t][1], red[t + sr][1]);
            red[t][2] = fmaxf(red[t][2], red[t + sr][2]);
        }
        __syncthreads();
    }
    m0 = red[0][0]; m1 = red[0][1]; m2 = red[0][2];
    // phase 2: weighted accumulate of x rows + weight sums
    __shared__ int ssrc[64];
    __shared__ float sw[64][H1];
    float acc0 = 0.f, acc1 = 0.f, acc2 = 0.f;
    float ps0 = 0.f, ps1 = 0.f, ps2 = 0.f;
    for (int base = e0; base < e1; base += 64) {
        int c = min(64, e1 - base);
        __syncthreads();
        if (t < c) {
            int s = csr_src[base + t];
            ssrc[t] = s;
            float w0 = __expf(lrelu(as1[s * H1 + 0] + adv0) - m0);
            float w1 = __expf(lrelu(as1[s * H1 + 1] + adv1) - m1);
            float w2 = __expf(lrelu(as1[s * H1 + 2] + adv2) - m2);
            sw[t][0] = w0; sw[t][1] = w1; sw[t][2] = w2;
            ps0 += w0; ps1 += w1; ps2 += w2;
        }
        __syncthreads();
        if (t < FIN) {
            for (int j = 0; j < c; j++) {
                float xv = x[ssrc[j] * FIN + t];
                acc0 += xv * sw[j][0];
                acc1 += xv * sw[j][1];
                acc2 += xv * sw[j][2];
            }
        }
    }
    __syncthreads();
    red[t][0] = ps0; red[t][1] = ps1; red[t][2] = ps2;
    __syncthreads();
    for (int sr = 64; sr > 0; sr >>= 1) {
        if (t < sr) {
            red[t][0] += red[t + sr][0];
            red[t][1] += red[t + sr][1];
            red[t][2] += red[t + sr][2];
        }
        __syncthreads();
    }
    float i0 = 1.f / red[0][0], i1 = 1.f / red[0][1], i2 = 1.f / red[0][2];
    if (t < FIN) {
        xagg[n * F1 + 0 * FIN + t] = acc0 * i0;
        xagg[n * F1 + 1 * FIN + t] = acc1 * i1;
        xagg[n * F1 + 2 * FIN + t] = acc2 * i2;
    }
}

// ===== per-head transform: h1a = ELU(xagg @ W1_h + b1), W1_h in LDS =====
__global__ __launch_bounds__(128) void k_gemm1h(const float* __restrict__ xagg,
                                                const float* __restrict__ W1,
                                                const float* __restrict__ b1,
                                                float* __restrict__ h1a) {
    int head = blockIdx.y;
    int rb = blockIdx.x * 64;
    int t = threadIdx.x;
    __shared__ float W1s[FIN * FIN];
    for (int i = t; i < FIN * FIN; i += 128) {
        int k = i / FIN, d = i % FIN;
        W1s[i] = W1[k * F1 + head * FIN + d];
    }
    __shared__ float xs[8][FIN];
    float bv = (t < FIN) ? b1[head * FIN + t] : 0.f;
    __syncthreads();
    for (int r0 = rb; r0 < rb + 64; r0 += 8) {
        for (int i = t; i < 8 * FIN; i += 128) {
            int r = i / FIN, k = i % FIN;
            int row = r0 + r;
            xs[r][k] = (row < NN) ? xagg[row * F1 + head * FIN + k] : 0.f;
        }
        __syncthreads();
        if (t < FIN) {
            float a[8] = {0, 0, 0, 0, 0, 0, 0, 0};
            for (int k = 0; k < FIN; k++) {
                float w = W1s[k * FIN + t];
#pragma unroll
                for (int r = 0; r < 8; r++) a[r] += xs[r][k] * w;
            }
#pragma unroll
            for (int r = 0; r < 8; r++) {
                int row = r0 + r;
                if (row < NN) {
                    float v = a[r] + bv;
                    h1a[row * F1 + head * FIN + t] = v > 0.f ? v : expm1f(v);
                }
            }
        }
        __syncthreads();
    }
}

// ===== GEMM2: h2 = h1a @ W2   [N,342]x[342,128], 16 rows/block =====
__global__ __launch_bounds__(256) void k_gemm2(const float* __restrict__ h1a,
                                               const float* __restrict__ W2,
                                               float* __restrict__ h2) {
    int rb = blockIdx.x * 16;
    int t = threadIdx.x;
    int col = t & 127, half = t >> 7;
    __shared__ float xs[16][F1];
    for (int i = t; i < 16 * F1; i += 256) {
        int r = i / F1, k = i % F1;
        int row = rb + r;
        xs[r][k] = (row < NN) ? h1a[row * F1 + k] : 0.f;
    }
    __syncthreads();
    float a[8] = {0, 0, 0, 0, 0, 0, 0, 0};
    for (int k = 0; k < F1; k++) {
        float w = W2[k * D2 + col];
#pragma unroll
        for (int r = 0; r < 8; r++) a[r] += xs[half * 8 + r][k] * w;
    }
#pragma unroll
    for (int r = 0; r < 8; r++) {
        int row = rb + half * 8 + r;
        if (row < NN) h2[row * D2 + col] = a[r];
    }
}

// ===== alpha2: per-node dot(h2_row, a_src2/a_dst2) =====
__global__ __launch_bounds__(256) void k_alpha2(const float* __restrict__ h2,
                                                const float* __restrict__ aS,
                                                const float* __restrict__ aD,
                                                float* __restrict__ as2,
                                                float* __restrict__ ad2) {
    int n = blockIdx.x * 4 + (threadIdx.x >> 6);
    int l = threadIdx.x & 63;
    if (n >= NN) return;
    float v0 = h2[n * D2 + l], v1 = h2[n * D2 + 64 + l];
    float ps = v0 * aS[l] + v1 * aS[64 + l];
    float pd = v0 * aD[l] + v1 * aD[64 + l];
    for (int o = 32; o > 0; o >>= 1) {
        ps += __shfl_down(ps, o);
        pd += __shfl_down(pd, o);
    }
    if (l == 0) {
        as2[n] = ps;
        ad2[n] = pd;
    }
}

// ===== layer-2: fused max/softmax-sum/aggregate of h2 =====
__global__ __launch_bounds__(128) void k_agg2f(const float* __restrict__ h2,
                                               const float* __restrict__ as2,
                                               const float* __restrict__ ad2,
                                               const int* __restrict__ off,
                                               const int* __restrict__ csr_src,
                                               const float* __restrict__ b2,
                                               float* __restrict__ h3) {
    int n = blockIdx.x, t = threadIdx.x;
    int e0 = off[n], e1 = off[n + 1];
    float adv = ad2[n];
    float mx = -1e30f;
    for (int e = e0 + t; e < e1; e += 128)
        mx = fmaxf(mx, lrelu(as2[csr_src[e]] + adv));
    __shared__ float red[128];
    red[t] = mx;
    __syncthreads();
    for (int sr = 64; sr > 0; sr >>= 1) {
        if (t < sr) red[t] = fmaxf(red[t], red[t + sr]);
        __syncthreads();
    }
    float m = red[0];
    __shared__ int ssrc[64];
    __shared__ float sw[64];
    float acc = 0.f, ps = 0.f;
    for (int base = e0; base < e1; base += 64) {
        int c = min(64, e1 - base);
        __syncthreads();
        if (t < c) {
            int s = csr_src[base + t];
            ssrc[t] = s;
            float w = __expf(lrelu(as2[s] + adv) - m);
            sw[t] = w;
            ps += w;
        }
        __syncthreads();
        for (int j = 0; j < c; j++) acc += h2[ssrc[j] * D2 + t] * sw[j];
    }
    __syncthreads();
    red[t] = ps;
    __syncthreads();
    for (int sr = 64; sr > 0; sr >>= 1) {
        if (t < sr) red[t] += red[t + sr];
        __syncthreads();
    }
    float v = acc / red[0] + b2[t];
    h3[n * D2 + t] = fmaxf(v, 0.f);
}

// ===== pool: 8-way partial segment-max via encoded atomicMax =====
__global__ __launch_bounds__(128) void k_pool(const float* __restrict__ h3,
                                              unsigned* __restrict__ poolbuf) {
    int g = blockIdx.x, part = blockIdx.y, t = threadIdx.x;
    int n0 = (g * NN + GG - 1) / GG;
    int n1 = ((g + 1) * NN + GG - 1) / GG;
    int cnt = n1 - n0, ch = (cnt + 7) / 8;
    int s0 = n0 + part * ch, s1 = min(s0 + ch, n1);
    float mx = -1e30f;
    for (int n = s0; n < s1; n++) mx = fmaxf(mx, h3[n * D2 + t]);
    if (s0 < s1) atomicMax(&poolbuf[g * D2 + t], fenc(mx));
}

// ===== MLP head =====
__global__ __launch_bounds__(128) void k_mlp(const unsigned* __restrict__ poolbuf,
                                             const float* __restrict__ Wg,
                                             const float* __restrict__ bg,
                                             const float* __restrict__ Wf1,
                                             const float* __restrict__ bf1,
                                             const float* __restrict__ Wf2,
                                             const float* __restrict__ bf2,
                                             const float* __restrict__ Wo,
                                             const float* __restrict__ bo,
                                             float* __restrict__ out) {
    int g = blockIdx.x;
    int t = threadIdx.x;
    __shared__ float pool[D2];
    __shared__ float a1[64];
    __shared__ float a2[32];
    __shared__ float a3[16];
    pool[t] = fdec(poolbuf[g * D2 + t]);
    __syncthreads();
    if (t < 64) {
        float acc = bg[t];
        for (int k = 0; k < D2; k++) acc += pool[k] * Wg[k * 64 + t];
        a1[t] = fmaxf(acc, 0.f);
    }
    __syncthreads();
    if (t < 32) {
        float acc = bf1[t];
        for (int k = 0; k < 64; k++) acc += a1[k] * Wf1[k * 32 + t];
        a2[t] = fmaxf(acc, 0.f);
    }
    __syncthreads();
    if (t < 16) {
        float acc = bf2[t];
        for (int k = 0; k < 32; k++) acc += a2[k] * Wf2[k * 16 + t];
        a3[t] = fmaxf(acc, 0.f);
    }
    __syncthreads();
    if (t == 0) {
        float acc = bo[0];
        for (int k = 0; k < 16; k++) acc += a3[k] * Wo[k];
        out[g] = acc;
    }
}

extern "C" void kernel_launch(void* const* d_in, const int* in_sizes, int n_in,
                              void* d_out, int out_size, void* d_ws, size_t ws_size,
                              hipStream_t stream) {
    const float* x = (const float*)d_in[0];
    const int* ei = (const int*)d_in[1];
    const float* W1 = (const float*)d_in[3];
    const float* aS1 = (const float*)d_in[4];
    const float* aD1 = (const float*)d_in[5];
    const float* b1 = (const float*)d_in[6];
    const float* W2 = (const float*)d_in[7];
    const float* aS2 = (const float*)d_in[8];
    const float* aD2 = (const float*)d_in[9];
    const float* b2 = (const float*)d_in[10];
    const float* Wg = (const float*)d_in[11];
    const float* bg = (const float*)d_in[12];
    const float* Wf1 = (const float*)d_in[13];
    const float* bf1 = (const float*)d_in[14];
    const float* Wf2 = (const float*)d_in[15];
    const float* bf2 = (const float*)d_in[16];
    const float* Wo = (const float*)d_in[17];
    const float* bo = (const float*)d_in[18];
    float* out = (float*)d_out;

    const int* src = ei;
    const int* dst = ei + EE;

    char* ws = (char*)d_ws;
    size_t o = 0;
    auto alloc = [&](size_t bytes) -> char* {
        char* p = ws + o;
        o += (bytes + 255) & ~(size_t)255;
        return p;
    };
    float* was = (float*)alloc((size_t)FIN * H1 * 4);
    float* wad = (float*)alloc((size_t)FIN * H1 * 4);
    float* as1 = (float*)alloc((size_t)NN * H1 * 4);
    float* ad1 = (float*)alloc((size_t)NN * H1 * 4);
    int* cnt = (int*)alloc((size_t)NN * 4);
    int* off = (int*)alloc((size_t)(NN + 1) * 4);
    int* cur = (int*)alloc((size_t)NN * 4);
    int* csr_src = (int*)alloc((size_t)EE * 4);
    float* xagg = (float*)alloc((size_t)NN * F1 * 4);
    float* h1a = (float*)alloc((size_t)NN * F1 * 4);
    float* h2 = (float*)alloc((size_t)NN * D2 * 4);
    float* as2 = (float*)alloc((size_t)NN * 4);
    float* ad2 = (float*)alloc((size_t)NN * 4);
    float* h3 = (float*)alloc((size_t)NN * D2 * 4);
    unsigned* poolbuf = (unsigned*)alloc((size_t)GG * D2 * 4);
    (void)ws_size;

    hipMemsetAsync(cnt, 0, (size_t)NN * 4, stream);
    hipMemsetAsync(cur, 0, (size_t)NN * 4, stream);
    hipMemsetAsync(poolbuf, 0, (size_t)GG * D2 * 4, stream);

    const int EB = (EE + 255) / 256;

    k_wa<<<(2 * FIN * H1 + 255) / 256, 256, 0, stream>>>(W1, aS1, aD1, was, wad);
    k_alpha1x<<<(NN + 3) / 4, 256, 0, stream>>>(x, was, wad, as1, ad1);
    k_count<<<EB, 256, 0, stream>>>(dst, cnt);
    k_scan<<<1, 1024, 0, stream>>>(cnt, off);
    k_scatter<<<EB, 256, 0, stream>>>(src, dst, off, cur, csr_src);
    k_aggx<<<NN, 128, 0, stream>>>(x, as1, ad1, off, csr_src, xagg);
    k_gemm1h<<<dim3((NN + 63) / 64, H1), 128, 0, stream>>>(xagg, W1, b1, h1a);
    k_gemm2<<<(NN + 15) / 16, 256, 0, stream>>>(h1a, W2, h2);
    k_alpha2<<<(NN + 3) / 4, 256, 0, stream>>>(h2, aS2, aD2, as2, ad2);
    k_agg2f<<<NN, 128, 0, stream>>>(h2, as2, ad2, off, csr_src, b2, h3);
    k_pool<<<dim3(GG, 8), 128, 0, stream>>>(h3, poolbuf);
    k_mlp<<<GG, 128, 0, stream>>>(poolbuf, Wg, bg, Wf1, bf1, Wf2, bf2, Wo, bo, out);
}

// Round 3
// 368.043 us; speedup vs baseline: 1.9747x; 1.1935x over previous
//
#include <hip/hip_runtime.h>

#define NN 20000
#define EE 660000      // 640000 + 20000 self loops
#define GG 64
#define FIN 114
#define H1 3
#define F1 342         // H1*FIN
#define D2 128
#define NEG 0.2f
#define KP 116         // FIN padded to multiple of 4

__device__ inline unsigned fenc(float f) {
    unsigned u = __float_as_uint(f);
    return (u & 0x80000000u) ? ~u : (u | 0x80000000u);
}
__device__ inline float fdec(unsigned u) {
    return (u & 0x80000000u) ? __uint_as_float(u & 0x7FFFFFFFu) : __uint_as_float(~u);
}
__device__ inline float lrelu(float x) { return x > 0.f ? x : NEG * x; }

// ===== fold a_src/a_dst through W1: was[k*3+h] = sum_d W1[k, h*114+d] * aS[h,d] =====
__global__ void k_wa(const float* __restrict__ W1, const float* __restrict__ aS,
                     const float* __restrict__ aD, float* __restrict__ was,
                     float* __restrict__ wad) {
    int tid = blockIdx.x * 256 + threadIdx.x;
    if (tid >= 2 * FIN * H1) return;
    int which = tid >= FIN * H1;
    int i = which ? tid - FIN * H1 : tid;
    int k = i / H1, h = i % H1;
    const float* a = which ? aD : aS;
    float s = 0.f;
    for (int d = 0; d < FIN; d++) s += W1[k * F1 + h * FIN + d] * a[h * FIN + d];
    (which ? wad : was)[i] = s;
}

// ===== weight pre-transpose + pad =====
// W1T[h][c][k] : [3][128][116], = W1[k*342 + h*114 + c] if c<114 && k<114 else 0
__global__ void k_prep1(const float* __restrict__ W1, float* __restrict__ W1T) {
    int tid = blockIdx.x * 256 + threadIdx.x;
    if (tid >= H1 * 128 * KP) return;
    int h = tid / (128 * KP);
    int rem = tid - h * 128 * KP;
    int c = rem / KP, k = rem % KP;
    W1T[tid] = (c < FIN && k < FIN) ? W1[k * F1 + h * FIN + c] : 0.f;
}
// W2T[c][ch*116+k] : [128][348], = W2[(ch*114+k)*128 + c] if k<114 else 0
__global__ void k_prep2(const float* __restrict__ W2, float* __restrict__ W2T) {
    int tid = blockIdx.x * 256 + threadIdx.x;
    if (tid >= 128 * 3 * KP) return;
    int c = tid / (3 * KP);
    int pos = tid - c * 3 * KP;
    int ch = pos / KP, k = pos % KP;
    W2T[tid] = (k < FIN) ? W2[(ch * FIN + k) * D2 + c] : 0.f;
}

// ===== as1/ad1 = x @ was/wad =====
__global__ __launch_bounds__(256) void k_alpha1x(const float* __restrict__ x,
                                                 const float* __restrict__ was,
                                                 const float* __restrict__ wad,
                                                 float* __restrict__ as1,
                                                 float* __restrict__ ad1) {
    int n = blockIdx.x * 4 + (threadIdx.x >> 6);
    int l = threadIdx.x & 63;
    if (n >= NN) return;
    float x0 = x[n * FIN + l];
    float x1 = (l < FIN - 64) ? x[n * FIN + 64 + l] : 0.f;
    float s[H1], d[H1];
#pragma unroll
    for (int h = 0; h < H1; h++) {
        float w0s = was[l * H1 + h], w0d = wad[l * H1 + h];
        float w1s = (l < FIN - 64) ? was[(64 + l) * H1 + h] : 0.f;
        float w1d = (l < FIN - 64) ? wad[(64 + l) * H1 + h] : 0.f;
        s[h] = x0 * w0s + x1 * w1s;
        d[h] = x0 * w0d + x1 * w1d;
    }
#pragma unroll
    for (int o = 32; o > 0; o >>= 1) {
#pragma unroll
        for (int h = 0; h < H1; h++) {
            s[h] += __shfl_down(s[h], o);
            d[h] += __shfl_down(d[h], o);
        }
    }
    if (l == 0) {
#pragma unroll
        for (int h = 0; h < H1; h++) {
            as1[n * H1 + h] = s[h];
            ad1[n * H1 + h] = d[h];
        }
    }
}

// ===================== CSR build =====================
__global__ void k_count(const int* __restrict__ dst, int* __restrict__ cnt) {
    int e = blockIdx.x * 256 + threadIdx.x;
    if (e < EE) atomicAdd(&cnt[dst[e]], 1);
}

__global__ __launch_bounds__(1024) void k_scan(const int* __restrict__ cnt,
                                               int* __restrict__ off) {
    __shared__ int part[1024];
    int t = threadIdx.x;
    const int CH = 20;
    int loc[CH];
    int s = 0;
    int base = t * CH;
    for (int i = 0; i < CH; i++) {
        int idx = base + i;
        int v = (idx < NN) ? cnt[idx] : 0;
        loc[i] = s;
        s += v;
    }
    part[t] = s;
    __syncthreads();
    for (int d = 1; d < 1024; d <<= 1) {
        int v = (t >= d) ? part[t - d] : 0;
        __syncthreads();
        part[t] += v;
        __syncthreads();
    }
    int pre = (t == 0) ? 0 : part[t - 1];
    for (int i = 0; i < CH; i++) {
        int idx = base + i;
        if (idx < NN) off[idx] = pre + loc[i];
    }
    if (t == 1023) off[NN] = part[1023];
}

__global__ void k_scatter(const int* __restrict__ src, const int* __restrict__ dst,
                          const int* __restrict__ off, int* __restrict__ cur,
                          int* __restrict__ csr_src) {
    int e = blockIdx.x * 256 + threadIdx.x;
    if (e < EE) {
        int d = dst[e];
        int pos = off[d] + atomicAdd(&cur[d], 1);
        csr_src[pos] = src[e];
    }
}

// ===== layer-1: fused max/softmax-sum/aggregate of x into xagg [N,3,114] =====
__global__ __launch_bounds__(128) void k_aggx(const float* __restrict__ x,
                                              const float* __restrict__ as1,
                                              const float* __restrict__ ad1,
                                              const int* __restrict__ off,
                                              const int* __restrict__ csr_src,
                                              float* __restrict__ xagg) {
    int n = blockIdx.x, t = threadIdx.x;
    int e0 = off[n], e1 = off[n + 1];
    float adv0 = ad1[n * H1 + 0], adv1 = ad1[n * H1 + 1], adv2 = ad1[n * H1 + 2];
    float m0 = -1e30f, m1 = -1e30f, m2 = -1e30f;
    for (int e = e0 + t; e < e1; e += 128) {
        int s = csr_src[e];
        m0 = fmaxf(m0, lrelu(as1[s * H1 + 0] + adv0));
        m1 = fmaxf(m1, lrelu(as1[s * H1 + 1] + adv1));
        m2 = fmaxf(m2, lrelu(as1[s * H1 + 2] + adv2));
    }
    __shared__ float red[128][H1];
    red[t][0] = m0; red[t][1] = m1; red[t][2] = m2;
    __syncthreads();
    for (int sr = 64; sr > 0; sr >>= 1) {
        if (t < sr) {
            red[t][0] = fmaxf(red[t][0], red[t + sr][0]);
            red[t][1] = fmaxf(red[t][1], red[t + sr][1]);
            red[t][2] = fmaxf(red[t][2], red[t + sr][2]);
        }
        __syncthreads();
    }
    m0 = red[0][0]; m1 = red[0][1]; m2 = red[0][2];
    __shared__ int ssrc[64];
    __shared__ float sw[64][H1];
    float acc0 = 0.f, acc1 = 0.f, acc2 = 0.f;
    float ps0 = 0.f, ps1 = 0.f, ps2 = 0.f;
    for (int base = e0; base < e1; base += 64) {
        int c = min(64, e1 - base);
        __syncthreads();
        if (t < c) {
            int s = csr_src[base + t];
            ssrc[t] = s;
            float w0 = __expf(lrelu(as1[s * H1 + 0] + adv0) - m0);
            float w1 = __expf(lrelu(as1[s * H1 + 1] + adv1) - m1);
            float w2 = __expf(lrelu(as1[s * H1 + 2] + adv2) - m2);
            sw[t][0] = w0; sw[t][1] = w1; sw[t][2] = w2;
            ps0 += w0; ps1 += w1; ps2 += w2;
        }
        __syncthreads();
        if (t < FIN) {
            for (int j = 0; j < c; j++) {
                float xv = x[ssrc[j] * FIN + t];
                acc0 += xv * sw[j][0];
                acc1 += xv * sw[j][1];
                acc2 += xv * sw[j][2];
            }
        }
    }
    __syncthreads();
    red[t][0] = ps0; red[t][1] = ps1; red[t][2] = ps2;
    __syncthreads();
    for (int sr = 64; sr > 0; sr >>= 1) {
        if (t < sr) {
            red[t][0] += red[t + sr][0];
            red[t][1] += red[t + sr][1];
            red[t][2] += red[t + sr][2];
        }
        __syncthreads();
    }
    float i0 = 1.f / red[0][0], i1 = 1.f / red[0][1], i2 = 1.f / red[0][2];
    if (t < FIN) {
        xagg[n * F1 + 0 * FIN + t] = acc0 * i0;
        xagg[n * F1 + 1 * FIN + t] = acc1 * i1;
        xagg[n * F1 + 2 * FIN + t] = acc2 * i2;
    }
}

// ===== GEMM1: h1a = ELU(xagg_h @ W1_h + b1), register-blocked 8x4 =====
// grid (ceil(N/64), 3), 256 threads. A-tile [64][116] LDS. B from L2 (W1T).
__global__ __launch_bounds__(256) void k_gemm1n(const float* __restrict__ xagg,
                                                const float* __restrict__ W1T,
                                                const float* __restrict__ b1,
                                                float* __restrict__ h1a) {
    int head = blockIdx.y;
    int rb = blockIdx.x * 64;
    int t = threadIdx.x;
    int rg = t >> 5;          // 0..7  -> rows rg*8 .. rg*8+7
    int cg = t & 31;          // 0..31 -> cols cg*4 .. cg*4+3
    int c0 = cg * 4;
    __shared__ float As[64][KP];
    for (int idx = t; idx < 64 * FIN; idx += 256) {
        int r = idx / FIN, k = idx - r * FIN;
        int row = rb + r;
        As[r][k] = (row < NN) ? xagg[row * F1 + head * FIN + k] : 0.f;
    }
    for (int idx = t; idx < 64 * 2; idx += 256) As[idx >> 1][FIN + (idx & 1)] = 0.f;
    __syncthreads();
    float acc[8][4] = {};
    const float* Bp = W1T + (head * 128 + c0) * KP;
    for (int kk = 0; kk < KP; kk += 4) {
        float4 b0 = *(const float4*)(Bp + 0 * KP + kk);
        float4 b1v = *(const float4*)(Bp + 1 * KP + kk);
        float4 b2v = *(const float4*)(Bp + 2 * KP + kk);
        float4 b3v = *(const float4*)(Bp + 3 * KP + kk);
#pragma unroll
        for (int r = 0; r < 8; r++) {
            float4 a = *(const float4*)(&As[rg * 8 + r][kk]);
            acc[r][0] += a.x * b0.x + a.y * b0.y + a.z * b0.z + a.w * b0.w;
            acc[r][1] += a.x * b1v.x + a.y * b1v.y + a.z * b1v.z + a.w * b1v.w;
            acc[r][2] += a.x * b2v.x + a.y * b2v.y + a.z * b2v.z + a.w * b2v.w;
            acc[r][3] += a.x * b3v.x + a.y * b3v.y + a.z * b3v.z + a.w * b3v.w;
        }
    }
    float bv[4];
#pragma unroll
    for (int j = 0; j < 4; j++)
        bv[j] = (c0 + j < FIN) ? b1[head * FIN + c0 + j] : 0.f;
#pragma unroll
    for (int r = 0; r < 8; r++) {
        int row = rb + rg * 8 + r;
        if (row >= NN) continue;
#pragma unroll
        for (int j = 0; j < 4; j++) {
            int c = c0 + j;
            if (c < FIN) {
                float v = acc[r][j] + bv[j];
                h1a[row * F1 + head * FIN + c] = v > 0.f ? v : expm1f(v);
            }
        }
    }
}

// ===== GEMM2: h2 = h1a @ W2, register-blocked 8x4, K in 3 chunks =====
__global__ __launch_bounds__(256) void k_gemm2n(const float* __restrict__ h1a,
                                                const float* __restrict__ W2T,
                                                float* __restrict__ h2) {
    int rb = blockIdx.x * 64;
    int t = threadIdx.x;
    int rg = t >> 5;
    int cg = t & 31;
    int c0 = cg * 4;
    __shared__ float As[64][KP];
    float acc[8][4] = {};
    for (int ch = 0; ch < 3; ch++) {
        __syncthreads();
        for (int idx = t; idx < 64 * FIN; idx += 256) {
            int r = idx / FIN, k = idx - r * FIN;
            int row = rb + r;
            As[r][k] = (row < NN) ? h1a[row * F1 + ch * FIN + k] : 0.f;
        }
        for (int idx = t; idx < 64 * 2; idx += 256) As[idx >> 1][FIN + (idx & 1)] = 0.f;
        __syncthreads();
        const float* Bp = W2T + c0 * (3 * KP) + ch * KP;
        for (int kk = 0; kk < KP; kk += 4) {
            float4 b0 = *(const float4*)(Bp + 0 * 3 * KP + kk);
            float4 b1v = *(const float4*)(Bp + 1 * 3 * KP + kk);
            float4 b2v = *(const float4*)(Bp + 2 * 3 * KP + kk);
            float4 b3v = *(const float4*)(Bp + 3 * 3 * KP + kk);
#pragma unroll
            for (int r = 0; r < 8; r++) {
                float4 a = *(const float4*)(&As[rg * 8 + r][kk]);
                acc[r][0] += a.x * b0.x + a.y * b0.y + a.z * b0.z + a.w * b0.w;
                acc[r][1] += a.x * b1v.x + a.y * b1v.y + a.z * b1v.z + a.w * b1v.w;
                acc[r][2] += a.x * b2v.x + a.y * b2v.y + a.z * b2v.z + a.w * b2v.w;
                acc[r][3] += a.x * b3v.x + a.y * b3v.y + a.z * b3v.z + a.w * b3v.w;
            }
        }
    }
#pragma unroll
    for (int r = 0; r < 8; r++) {
        int row = rb + rg * 8 + r;
        if (row < NN)
            *(float4*)(&h2[row * D2 + c0]) =
                make_float4(acc[r][0], acc[r][1], acc[r][2], acc[r][3]);
    }
}

// ===== alpha2: per-node dot(h2_row, a_src2/a_dst2) =====
__global__ __launch_bounds__(256) void k_alpha2(const float* __restrict__ h2,
                                                const float* __restrict__ aS,
                                                const float* __restrict__ aD,
                                                float* __restrict__ as2,
                                                float* __restrict__ ad2) {
    int n = blockIdx.x * 4 + (threadIdx.x >> 6);
    int l = threadIdx.x & 63;
    if (n >= NN) return;
    float v0 = h2[n * D2 + l], v1 = h2[n * D2 + 64 + l];
    float ps = v0 * aS[l] + v1 * aS[64 + l];
    float pd = v0 * aD[l] + v1 * aD[64 + l];
    for (int o = 32; o > 0; o >>= 1) {
        ps += __shfl_down(ps, o);
        pd += __shfl_down(pd, o);
    }
    if (l == 0) {
        as2[n] = ps;
        ad2[n] = pd;
    }
}

// ===== layer-2: fused max/softmax-sum/aggregate of h2 =====
__global__ __launch_bounds__(128) void k_agg2f(const float* __restrict__ h2,
                                               const float* __restrict__ as2,
                                               const float* __restrict__ ad2,
                                               const int* __restrict__ off,
                                               const int* __restrict__ csr_src,
                                               const float* __restrict__ b2,
                                               float* __restrict__ h3) {
    int n = blockIdx.x, t = threadIdx.x;
    int e0 = off[n], e1 = off[n + 1];
    float adv = ad2[n];
    float mx = -1e30f;
    for (int e = e0 + t; e < e1; e += 128)
        mx = fmaxf(mx, lrelu(as2[csr_src[e]] + adv));
    __shared__ float red[128];
    red[t] = mx;
    __syncthreads();
    for (int sr = 64; sr > 0; sr >>= 1) {
        if (t < sr) red[t] = fmaxf(red[t], red[t + sr]);
        __syncthreads();
    }
    float m = red[0];
    __shared__ int ssrc[64];
    __shared__ float sw[64];
    float acc = 0.f, ps = 0.f;
    for (int base = e0; base < e1; base += 64) {
        int c = min(64, e1 - base);
        __syncthreads();
        if (t < c) {
            int s = csr_src[base + t];
            ssrc[t] = s;
            float w = __expf(lrelu(as2[s] + adv) - m);
            sw[t] = w;
            ps += w;
        }
        __syncthreads();
        for (int j = 0; j < c; j++) acc += h2[ssrc[j] * D2 + t] * sw[j];
    }
    __syncthreads();
    red[t] = ps;
    __syncthreads();
    for (int sr = 64; sr > 0; sr >>= 1) {
        if (t < sr) red[t] += red[t + sr];
        __syncthreads();
    }
    float v = acc / red[0] + b2[t];
    h3[n * D2 + t] = fmaxf(v, 0.f);
}

// ===== pool: 8-way partial segment-max via encoded atomicMax =====
__global__ __launch_bounds__(128) void k_pool(const float* __restrict__ h3,
                                              unsigned* __restrict__ poolbuf) {
    int g = blockIdx.x, part = blockIdx.y, t = threadIdx.x;
    int n0 = (g * NN + GG - 1) / GG;
    int n1 = ((g + 1) * NN + GG - 1) / GG;
    int cnt = n1 - n0, ch = (cnt + 7) / 8;
    int s0 = n0 + part * ch, s1 = min(s0 + ch, n1);
    float mx = -1e30f;
    for (int n = s0; n < s1; n++) mx = fmaxf(mx, h3[n * D2 + t]);
    if (s0 < s1) atomicMax(&poolbuf[g * D2 + t], fenc(mx));
}

// ===== MLP head =====
__global__ __launch_bounds__(128) void k_mlp(const unsigned* __restrict__ poolbuf,
                                             const float* __restrict__ Wg,
                                             const float* __restrict__ bg,
                                             const float* __restrict__ Wf1,
                                             const float* __restrict__ bf1,
                                             const float* __restrict__ Wf2,
                                             const float* __restrict__ bf2,
                                             const float* __restrict__ Wo,
                                             const float* __restrict__ bo,
                                             float* __restrict__ out) {
    int g = blockIdx.x;
    int t = threadIdx.x;
    __shared__ float pool[D2];
    __shared__ float a1[64];
    __shared__ float a2[32];
    __shared__ float a3[16];
    pool[t] = fdec(poolbuf[g * D2 + t]);
    __syncthreads();
    if (t < 64) {
        float acc = bg[t];
        for (int k = 0; k < D2; k++) acc += pool[k] * Wg[k * 64 + t];
        a1[t] = fmaxf(acc, 0.f);
    }
    __syncthreads();
    if (t < 32) {
        float acc = bf1[t];
        for (int k = 0; k < 64; k++) acc += a1[k] * Wf1[k * 32 + t];
        a2[t] = fmaxf(acc, 0.f);
    }
    __syncthreads();
    if (t < 16) {
        float acc = bf2[t];
        for (int k = 0; k < 32; k++) acc += a2[k] * Wf2[k * 16 + t];
        a3[t] = fmaxf(acc, 0.f);
    }
    __syncthreads();
    if (t == 0) {
        float acc = bo[0];
        for (int k = 0; k < 16; k++) acc += a3[k] * Wo[k];
        out[g] = acc;
    }
}

extern "C" void kernel_launch(void* const* d_in, const int* in_sizes, int n_in,
                              void* d_out, int out_size, void* d_ws, size_t ws_size,
                              hipStream_t stream) {
    const float* x = (const float*)d_in[0];
    const int* ei = (const int*)d_in[1];
    const float* W1 = (const float*)d_in[3];
    const float* aS1 = (const float*)d_in[4];
    const float* aD1 = (const float*)d_in[5];
    const float* b1 = (const float*)d_in[6];
    const float* W2 = (const float*)d_in[7];
    const float* aS2 = (const float*)d_in[8];
    const float* aD2 = (const float*)d_in[9];
    const float* b2 = (const float*)d_in[10];
    const float* Wg = (const float*)d_in[11];
    const float* bg = (const float*)d_in[12];
    const float* Wf1 = (const float*)d_in[13];
    const float* bf1 = (const float*)d_in[14];
    const float* Wf2 = (const float*)d_in[15];
    const float* bf2 = (const float*)d_in[16];
    const float* Wo = (const float*)d_in[17];
    const float* bo = (const float*)d_in[18];
    float* out = (float*)d_out;

    const int* src = ei;
    const int* dst = ei + EE;

    char* ws = (char*)d_ws;
    size_t o = 0;
    auto alloc = [&](size_t bytes) -> char* {
        char* p = ws + o;
        o += (bytes + 255) & ~(size_t)255;
        return p;
    };
    float* was = (float*)alloc((size_t)FIN * H1 * 4);
    float* wad = (float*)alloc((size_t)FIN * H1 * 4);
    float* W1T = (float*)alloc((size_t)H1 * 128 * KP * 4);
    float* W2T = (float*)alloc((size_t)128 * 3 * KP * 4);
    float* as1 = (float*)alloc((size_t)NN * H1 * 4);
    float* ad1 = (float*)alloc((size_t)NN * H1 * 4);
    int* cnt = (int*)alloc((size_t)NN * 4);
    int* off = (int*)alloc((size_t)(NN + 1) * 4);
    int* cur = (int*)alloc((size_t)NN * 4);
    int* csr_src = (int*)alloc((size_t)EE * 4);
    float* xagg = (float*)alloc((size_t)NN * F1 * 4);
    float* h1a = (float*)alloc((size_t)NN * F1 * 4);
    float* h2 = (float*)alloc((size_t)NN * D2 * 4);
    float* as2 = (float*)alloc((size_t)NN * 4);
    float* ad2 = (float*)alloc((size_t)NN * 4);
    float* h3 = (float*)alloc((size_t)NN * D2 * 4);
    unsigned* poolbuf = (unsigned*)alloc((size_t)GG * D2 * 4);
    (void)ws_size;

    hipMemsetAsync(cnt, 0, (size_t)NN * 4, stream);
    hipMemsetAsync(cur, 0, (size_t)NN * 4, stream);
    hipMemsetAsync(poolbuf, 0, (size_t)GG * D2 * 4, stream);

    const int EB = (EE + 255) / 256;

    k_wa<<<(2 * FIN * H1 + 255) / 256, 256, 0, stream>>>(W1, aS1, aD1, was, wad);
    k_prep1<<<(H1 * 128 * KP + 255) / 256, 256, 0, stream>>>(W1, W1T);
    k_prep2<<<(128 * 3 * KP + 255) / 256, 256, 0, stream>>>(W2, W2T);
    k_alpha1x<<<(NN + 3) / 4, 256, 0, stream>>>(x, was, wad, as1, ad1);
    k_count<<<EB, 256, 0, stream>>>(dst, cnt);
    k_scan<<<1, 1024, 0, stream>>>(cnt, off);
    k_scatter<<<EB, 256, 0, stream>>>(src, dst, off, cur, csr_src);
    k_aggx<<<NN, 128, 0, stream>>>(x, as1, ad1, off, csr_src, xagg);
    k_gemm1n<<<dim3((NN + 63) / 64, H1), 256, 0, stream>>>(xagg, W1T, b1, h1a);
    k_gemm2n<<<(NN + 63) / 64, 256, 0, stream>>>(h1a, W2T, h2);
    k_alpha2<<<(NN + 3) / 4, 256, 0, stream>>>(h2, aS2, aD2, as2, ad2);
    k_agg2f<<<NN, 128, 0, stream>>>(h2, as2, ad2, off, csr_src, b2, h3);
    k_pool<<<dim3(GG, 8), 128, 0, stream>>>(h3, poolbuf);
    k_mlp<<<GG, 128, 0, stream>>>(poolbuf, Wg, bg, Wf1, bf1, Wf2, bf2, Wo, bo, out);
}